// Round 13
// baseline (260.574 us; speedup 1.0000x reference)
//
#include <hip/hip_runtime.h>
#include <math.h>

typedef unsigned int uint;
typedef unsigned short ushort;

typedef __bf16 bf16x8 __attribute__((ext_vector_type(8)));
typedef float f32x4 __attribute__((ext_vector_type(4)));
typedef float f32x2 __attribute__((ext_vector_type(2)));

#define MAXNB 512  // n < 65536 -> NB = ceil(n/128) <= 512

// ---------------- bf16 helpers (RNE pack, shift unpack) ----------------

__device__ inline uint bf16rne(float f) {
    uint u = __float_as_uint(f);
    uint r = ((u >> 16) & 1u) + 0x7fffu;
    return (u + r) >> 16;
}
__device__ inline uint packbf2(float a, float b) {
    return bf16rne(a) | (bf16rne(b) << 16);
}
__device__ inline float unlo(uint v) { return __uint_as_float(v << 16); }
__device__ inline float unhi(uint v) { return __uint_as_float(v & 0xffff0000u); }

// ---------------- graph prep: deterministic bucketed CSR build ----------------
// bucket = dst>>7. Tiles of 2048 edges.

// fused: [0..NT1) per-tile LDS histogram + global degree count | [NT1..) weight prep
__global__ __launch_bounds__(256) void k_hist_prep(const int* __restrict__ dst, int E,
                                                   int NT1, ushort* __restrict__ rank,
                                                   int* __restrict__ C, int NB,
                                                   int* __restrict__ cnt,
                                                   const float* __restrict__ W0,
                                                   const float* __restrict__ W1,
                                                   const float* __restrict__ W2,
                                                   ushort* __restrict__ WT0,
                                                   ushort* __restrict__ WT1,
                                                   ushort* __restrict__ WT2) {
    __shared__ int hist[MAXNB];
    int tid = threadIdx.x, b = blockIdx.x;
    if (b < NT1) {
        for (int i = tid; i < MAXNB; i += 256) hist[i] = 0;
        __syncthreads();
        int e0 = b * 2048;
#pragma unroll
        for (int i = 0; i < 8; ++i) {
            int e = e0 + i * 256 + tid;
            if (e < E) {
                int d = dst[e];
                rank[e] = (ushort)atomicAdd(&hist[d >> 7], 1);  // LDS atomic
                atomicAdd(&cnt[d], 1);                          // fire-and-forget global
            }
        }
        __syncthreads();
        for (int be = tid; be < NB; be += 256) C[(size_t)be * NT1 + b] = hist[be];
    } else {
        int idx = (b - NT1) * 256 + tid;
        if (idx < 16384) {
            int c = idx >> 7, k = idx & 127;
            WT0[idx] = (ushort)bf16rne(W0[k * 128 + c]);
            WT1[idx] = (ushort)bf16rne(W1[k * 128 + c]);
        } else if (idx < 16384 + 8192) {
            int j = idx - 16384;
            int c = j >> 7, k = j & 127;
            WT2[j] = (c < 40) ? (ushort)bf16rne(W2[k * 40 + c]) : (ushort)0;
        }
    }
}

__global__ __launch_bounds__(64) void k_cscan(int* __restrict__ C, int NT1,
                                              int* __restrict__ T) {
    int be = blockIdx.x, lane = threadIdx.x;
    size_t base = (size_t)be * NT1;
    int carry = 0;
    for (int c0 = 0; c0 < NT1; c0 += 64) {
        int idx = c0 + lane;
        int v = (idx < NT1) ? C[base + idx] : 0;
        int s = v;
#pragma unroll
        for (int d = 1; d < 64; d <<= 1) {
            int o = __shfl_up(s, d);
            if (lane >= d) s += o;
        }
        if (idx < NT1) C[base + idx] = carry + s - v;
        carry += __shfl(s, 63);
    }
    if (lane == 0) T[be] = carry;
}

__global__ __launch_bounds__(64) void k_bscan(const int* __restrict__ T, int NB,
                                              int* __restrict__ tbase,
                                              int* __restrict__ cbase) {
    int lane = threadIdx.x;
    int c1 = 0, c2 = 0;
    for (int b0 = 0; b0 < NB; b0 += 64) {
        int idx = b0 + lane;
        int t = (idx < NB) ? T[idx] : 0;
        int u = t + 1024;
        int s1 = t, s2 = u;
#pragma unroll
        for (int d = 1; d < 64; d <<= 1) {
            int o1 = __shfl_up(s1, d), o2 = __shfl_up(s2, d);
            if (lane >= d) { s1 += o1; s2 += o2; }
        }
        if (idx < NB) { tbase[idx] = c1 + s1 - t; cbase[idx] = c2 + s2 - u; }
        c1 += __shfl(s1, 63);
        c2 += __shfl(s2, 63);
    }
    if (lane == 0) tbase[NB] = c1;
}

// single final pass: block per bucket, scatter tmp -> csr (all writes in one bucket
// window = one XCD -> no false sharing). csr entry = {src:16 | bf16(w):16}.
__global__ __launch_bounds__(256) void k_p2(const uint* __restrict__ tmp,
                                            const int* __restrict__ tbase,
                                            const int* __restrict__ offs,
                                            const float* __restrict__ dinv,
                                            uint* __restrict__ csr) {
    __shared__ int cur[128];
    int be = blockIdx.x, tid = threadIdx.x;
    if (tid < 128) cur[tid] = 0;
    __syncthreads();
    int j0 = tbase[be], j1 = tbase[be + 1];
    for (int j = j0 + tid; j < j1; j += 256) {
        uint v = tmp[j];
        int s = (int)(v & 0xffffu);
        int dl = (int)(v >> 16);
        int d = be * 128 + dl;
        int r = atomicAdd(&cur[dl], 1);  // LDS atomic
        uint wb = bf16rne(dinv[s] * dinv[d]) << 16;
        csr[offs[d] + r] = (uint)s | wb;
    }
}

// ---------------- MFMA GEMM body: H[n x F] = X[n x 128] @ W, WT = W^T[F x 128] ----
// wave = 16 rows x F cols; OUT8: pack D to fp8 e4m3 via quad shuffles + v_cvt_pk_fp8.
template <int F, bool F32IN, bool OUT8>
__device__ inline void mgemm_body(const void* __restrict__ Xv,
                                  const __bf16* __restrict__ WT,
                                  void* __restrict__ Hb, int n, int blk, int tid) {
    constexpr int NT = F / 16;  // 16-col tiles
    int lane = tid & 63;
    int wv = tid >> 6;
    int rbase = blk * 64 + wv * 16;
    if (rbase >= n) return;  // n % 16 == 0: strips fully valid or fully absent
    int m = lane & 15, quad = lane >> 4;

    bf16x8 a[4];
    if (F32IN) {
        const float* xrow = (const float*)Xv + (size_t)(rbase + m) * 128 + quad * 8;
#pragma unroll
        for (int ks = 0; ks < 4; ++ks) {
            float4 lo = *(const float4*)(xrow + ks * 32);
            float4 hi = *(const float4*)(xrow + ks * 32 + 4);
            union { ushort u[8]; bf16x8 v; } cv;
            cv.u[0] = (ushort)bf16rne(lo.x); cv.u[1] = (ushort)bf16rne(lo.y);
            cv.u[2] = (ushort)bf16rne(lo.z); cv.u[3] = (ushort)bf16rne(lo.w);
            cv.u[4] = (ushort)bf16rne(hi.x); cv.u[5] = (ushort)bf16rne(hi.y);
            cv.u[6] = (ushort)bf16rne(hi.z); cv.u[7] = (ushort)bf16rne(hi.w);
            a[ks] = cv.v;
        }
    } else {
        const __bf16* xrow = (const __bf16*)Xv + (size_t)(rbase + m) * 128 + quad * 8;
#pragma unroll
        for (int ks = 0; ks < 4; ++ks) a[ks] = *(const bf16x8*)(xrow + ks * 32);
    }

    f32x4 acc[NT];
#pragma unroll
    for (int t = 0; t < NT; ++t) acc[t] = (f32x4){0.f, 0.f, 0.f, 0.f};

#pragma unroll
    for (int t = 0; t < NT; ++t) {
        const __bf16* wrow = WT + (size_t)(t * 16 + m) * 128 + quad * 8;
#pragma unroll
        for (int ks = 0; ks < 4; ++ks) {
            bf16x8 b = *(const bf16x8*)(wrow + ks * 32);
            acc[t] = __builtin_amdgcn_mfma_f32_16x16x32_bf16(a[ks], b, acc[t], 0, 0, 0);
        }
    }

    if (OUT8) {
        uint* H8 = (uint*)Hb;  // row = F/4 uints (fp8 per feature)
#pragma unroll
        for (int t = 0; t < NT; ++t) {
#pragma unroll
            for (int r = 0; r < 4; ++r) {
                float v = acc[t][r];
                int s0 = lane & ~3;
                float v0 = __shfl(v, s0);
                float v1 = __shfl(v, s0 + 1);
                float v2 = __shfl(v, s0 + 2);
                float v3 = __shfl(v, s0 + 3);
                if ((m & 3) == 0) {
                    int pk = __builtin_amdgcn_cvt_pk_fp8_f32(v0, v1, 0, false);
                    pk = __builtin_amdgcn_cvt_pk_fp8_f32(v2, v3, pk, true);
                    int row = rbase + quad * 4 + r;
                    H8[(size_t)row * (F / 4) + t * 4 + (m >> 2)] = (uint)pk;
                }
            }
        }
    } else {
        ushort* Hs = (ushort*)Hb;
#pragma unroll
        for (int t = 0; t < NT; ++t) {
#pragma unroll
            for (int r = 0; r < 4; ++r) {
                int row = rbase + quad * 4 + r;
                Hs[(size_t)row * F + t * 16 + m] = (ushort)bf16rne(acc[t][r]);
            }
        }
    }
}

// fused grid: [0..P) edge scatter into tmp | [P..P+G) layer-0 GEMM | [P+G..) node alloc
__global__ __launch_bounds__(256) void k_place_gemm_alloc(
        const int* __restrict__ src, const int* __restrict__ dst, int E,
        int NT1, const ushort* __restrict__ rank, const int* __restrict__ C,
        const int* __restrict__ tbase, uint* __restrict__ tmp, int P, int G,
        const float* __restrict__ x, const __bf16* __restrict__ WT0,
        uint* __restrict__ H8,
        const int* __restrict__ cnt, const int* __restrict__ cbase,
        int* __restrict__ offs, int* __restrict__ ends, float* __restrict__ dinv, int n) {
    __shared__ int sinc[128];
    int b = blockIdx.x, tid = threadIdx.x;
    if (b < P) {
        int e = b * 256 + tid;
        if (e >= E) return;
        int d = dst[e];
        int be = d >> 7, t = e >> 11;
        int pos = tbase[be] + C[(size_t)be * NT1 + t] + (int)rank[e];
        tmp[pos] = (uint)src[e] | ((uint)(d & 127) << 16);
    } else if (b < P + G) {
        mgemm_body<128, true, true>(x, WT0, H8, n, b - P, tid);
    } else {
        int be = b - P - G;
        int i = be * 128 + (tid & 127);
        int c = 0, cp = 0;
        if (tid < 128) {
            c = (i < n) ? cnt[i] : 0;
            cp = (c + 7) & ~7;
            int lane = tid & 63;
            int s = cp;
#pragma unroll
            for (int d = 1; d < 64; d <<= 1) {
                int o = __shfl_up(s, d);
                if (lane >= d) s += o;
            }
            sinc[tid] = s;  // inclusive within wave
        }
        __syncthreads();
        if (tid < 128) {
            int base = (tid >= 64) ? sinc[63] : 0;
            int og = cbase[be] + base + sinc[tid] - cp;
            if (i < n) {
                offs[i] = og;
                ends[i] = og + c;
                dinv[i] = rsqrtf((float)(c + 1));  // +1 self loop
            }
        }
    }
}

template <int F, bool F32IN, bool OUT8>
__global__ __launch_bounds__(256) void k_mgemm(const void* __restrict__ Xv,
                                               const __bf16* __restrict__ WT,
                                               void* __restrict__ Hb, int n) {
    mgemm_body<F, F32IN, OUT8>(Xv, WT, Hb, n, blockIdx.x, threadIdx.x);
}

// ---------------- aggregation: y[i] = relu( sum_e w_e h[src_e] + dinv_i^2 h[i] + b ) --------
// fp8 h: row = 32 uints (128 fp8) = 2 lines/edge. wave = 2 nodes x 32 lanes;
// lane = 4 features. fp32 accumulate; bf16 packed out.
__global__ __launch_bounds__(256) void k_agg128(const uint* __restrict__ hb8,
                                                const int* __restrict__ offs,
                                                const int* __restrict__ ends,
                                                const uint* __restrict__ csr,
                                                const float* __restrict__ dinv,
                                                const float* __restrict__ bias,
                                                uint* __restrict__ out, int n) {
    int tid = threadIdx.x;
    int lane = tid & 63;
    int half = lane >> 5, l32 = lane & 31;
    int wid = blockIdx.x * 8 + ((tid >> 6) << 1) + half;
    if (wid >= n) return;
    float di = dinv[wid];
    float dd = di * di;
    uint t0 = hb8[(size_t)wid * 32 + l32];
    f32x2 s01 = __builtin_amdgcn_cvt_pk_f32_fp8((int)t0, false);
    f32x2 s23 = __builtin_amdgcn_cvt_pk_f32_fp8((int)t0, true);
    float4 acc = make_float4(s01[0] * dd, s01[1] * dd, s23[0] * dd, s23[1] * dd);
    int e0 = offs[wid];                       // multiple of 8
    int nchunk = (ends[wid] - e0 + 7) >> 3;
    const uint4* csrv = (const uint4*)(csr + e0);

    uint Pa[8], Pb[8];                        // packed {src | w_bf16}
    uint Ga[8], Gb[8];

    auto loadP = [&](int c, uint* p) {        // speculative final load stays in zero-pad
        uint4 v0 = csrv[2 * c];
        uint4 v1 = csrv[2 * c + 1];
        p[0] = v0.x; p[1] = v0.y; p[2] = v0.z; p[3] = v0.w;
        p[4] = v1.x; p[5] = v1.y; p[6] = v1.z; p[7] = v1.w;
    };
    auto gatherK = [&](const uint* p, uint* g) {
#pragma unroll
        for (int j = 0; j < 8; ++j)
            g[j] = hb8[(size_t)(p[j] & 0xffffu) * 32 + l32];
    };
    auto fmaK = [&](const uint* p, const uint* g) {
#pragma unroll
        for (int j = 0; j < 8; ++j) {
            float w = unhi(p[j]);
            f32x2 a01 = __builtin_amdgcn_cvt_pk_f32_fp8((int)g[j], false);
            f32x2 a23 = __builtin_amdgcn_cvt_pk_f32_fp8((int)g[j], true);
            acc.x = fmaf(w, a01[0], acc.x);
            acc.y = fmaf(w, a01[1], acc.y);
            acc.z = fmaf(w, a23[0], acc.z);
            acc.w = fmaf(w, a23[1], acc.w);
        }
    };

    if (nchunk > 0) {
        loadP(0, Pa);
        gatherK(Pa, Ga);
        loadP(1, Pb);
        int c = 0;
        while (true) {
            gatherK(Pb, Gb);   // chunk c+1 (entries pre-loaded)
            fmaK(Pa, Ga);      // chunk c (gathers issued an iter ago)
            if (++c >= nchunk) break;
            loadP(c + 1, Pa);
            gatherK(Pa, Ga);
            fmaK(Pb, Gb);
            if (++c >= nchunk) break;
            loadP(c + 1, Pb);
        }
    }

    float4 b = ((const float4*)bias)[l32];
    uint2 o;
    o.x = packbf2(fmaxf(acc.x + b.x, 0.f), fmaxf(acc.y + b.y, 0.f));
    o.y = packbf2(fmaxf(acc.z + b.z, 0.f), fmaxf(acc.w + b.w, 0.f));
    ((uint2*)out)[(size_t)wid * 32 + l32] = o;
}

// final layer: fp8 h (64 feats = 16 uints = 1 line/edge). wave = 4 nodes x 16 lanes,
// lane = 4 features; fused bias+relu+log_softmax over 16-lane groups (40 = 10 lanes x 4).
__global__ __launch_bounds__(256) void k_agg40(const uint* __restrict__ hb8,
                                               const int* __restrict__ offs,
                                               const int* __restrict__ ends,
                                               const uint* __restrict__ csr,
                                               const float* __restrict__ dinv,
                                               const float* __restrict__ bias,
                                               float* __restrict__ out, int n) {
    int tid = threadIdx.x;
    int lane = tid & 63;
    int quad = lane >> 4, l16 = lane & 15;
    int wid = blockIdx.x * 16 + ((tid >> 6) << 2) + quad;
    if (wid >= n) return;
    float di = dinv[wid];
    float dd = di * di;
    uint t0 = hb8[(size_t)wid * 16 + l16];
    f32x2 s01 = __builtin_amdgcn_cvt_pk_f32_fp8((int)t0, false);
    f32x2 s23 = __builtin_amdgcn_cvt_pk_f32_fp8((int)t0, true);
    float4 acc = make_float4(s01[0] * dd, s01[1] * dd, s23[0] * dd, s23[1] * dd);
    int e0 = offs[wid];                       // multiple of 8
    int nchunk = (ends[wid] - e0 + 7) >> 3;
    const uint4* csrv = (const uint4*)(csr + e0);

    uint Pa[8], Pb[8];
    uint Ga[8], Gb[8];

    auto loadP = [&](int c, uint* p) {        // quad-uniform broadcast loads
        uint4 v0 = csrv[2 * c];
        uint4 v1 = csrv[2 * c + 1];
        p[0] = v0.x; p[1] = v0.y; p[2] = v0.z; p[3] = v0.w;
        p[4] = v1.x; p[5] = v1.y; p[6] = v1.z; p[7] = v1.w;
    };
    auto gatherK = [&](const uint* p, uint* g) {
#pragma unroll
        for (int j = 0; j < 8; ++j)
            g[j] = hb8[(size_t)(p[j] & 0xffffu) * 16 + l16];
    };
    auto fmaK = [&](const uint* p, const uint* g) {
#pragma unroll
        for (int j = 0; j < 8; ++j) {
            float w = unhi(p[j]);
            f32x2 a01 = __builtin_amdgcn_cvt_pk_f32_fp8((int)g[j], false);
            f32x2 a23 = __builtin_amdgcn_cvt_pk_f32_fp8((int)g[j], true);
            acc.x = fmaf(w, a01[0], acc.x);
            acc.y = fmaf(w, a01[1], acc.y);
            acc.z = fmaf(w, a23[0], acc.z);
            acc.w = fmaf(w, a23[1], acc.w);
        }
    };

    if (nchunk > 0) {
        loadP(0, Pa);
        gatherK(Pa, Ga);
        loadP(1, Pb);
        int c = 0;
        while (true) {
            gatherK(Pb, Gb);
            fmaK(Pa, Ga);
            if (++c >= nchunk) break;
            loadP(c + 1, Pa);
            gatherK(Pa, Ga);
            fmaK(Pb, Gb);
            if (++c >= nchunk) break;
            loadP(c + 1, Pb);
        }
    }

    bool val = l16 < 10;                       // features l16*4..l16*4+3 valid iff l16<10
    float4 b4 = val ? ((const float4*)bias)[l16] : make_float4(0.f, 0.f, 0.f, 0.f);
    float v0 = val ? fmaxf(acc.x + b4.x, 0.f) : -INFINITY;
    float v1 = val ? fmaxf(acc.y + b4.y, 0.f) : -INFINITY;
    float v2 = val ? fmaxf(acc.z + b4.z, 0.f) : -INFINITY;
    float v3 = val ? fmaxf(acc.w + b4.w, 0.f) : -INFINITY;
    float m = fmaxf(fmaxf(v0, v1), fmaxf(v2, v3));
#pragma unroll
    for (int d = 8; d; d >>= 1) m = fmaxf(m, __shfl_xor(m, d));
    float ex = val ? (expf(v0 - m) + expf(v1 - m) + expf(v2 - m) + expf(v3 - m)) : 0.f;
#pragma unroll
    for (int d = 8; d; d >>= 1) ex += __shfl_xor(ex, d);
    float ls = logf(ex);
    if (val) {
        ((float4*)out)[(size_t)wid * 10 + l16] =
            make_float4(v0 - m - ls, v1 - m - ls, v2 - m - ls, v3 - m - ls);
    }
}

// ---------------- launch ----------------

extern "C" void kernel_launch(void* const* d_in, const int* in_sizes, int n_in,
                              void* d_out, int out_size, void* d_ws, size_t ws_size,
                              hipStream_t stream) {
    const float* x  = (const float*)d_in[0];
    const int*   ei = (const int*)d_in[1];
    const float* W0 = (const float*)d_in[2];
    const float* b0 = (const float*)d_in[3];
    const float* W1 = (const float*)d_in[4];
    const float* b1 = (const float*)d_in[5];
    const float* W2 = (const float*)d_in[6];
    const float* b2 = (const float*)d_in[7];
    float* out = (float*)d_out;

    int n = in_sizes[0] / 128;
    int E = in_sizes[1] / 2;
    const int* srcv = ei;
    const int* dstv = ei + E;
    int NB  = (n + 127) / 128;     // buckets (dst>>7), <= 512
    int NT1 = (E + 2047) / 2048;   // phase-1 tiles
    size_t csr_elems = (size_t)E + 1024 * (size_t)NB + 64;

    char* w = (char*)d_ws;
    auto alloc = [&](size_t bytes) {
        char* p = w;
        w += (bytes + 255) & ~(size_t)255;
        return p;
    };
    // --- zeroed region: csr (pads stay zero) + cnt contiguous -> ONE memset ---
    uint*   csr    = (uint*)alloc(csr_elems * 4);
    int*    cnt    = (int*)alloc((size_t)n * 4);
    size_t zbytes = (size_t)(w - (char*)csr);
    // --- rest ---
    int*    C      = (int*)alloc((size_t)NB * NT1 * 4);
    ushort* rank   = (ushort*)alloc((size_t)E * 2);
    uint*   tmp    = (uint*)alloc((size_t)E * 4);
    int*    T      = (int*)alloc((size_t)NB * 4);
    int*    tbase  = (int*)alloc((size_t)(NB + 1) * 4);
    int*    cbase  = (int*)alloc((size_t)NB * 4);
    int*    offs   = (int*)alloc((size_t)n * 4);
    int*    ends   = (int*)alloc((size_t)n * 4);
    float*  dinv   = (float*)alloc((size_t)n * 4);
    uint*   xb     = (uint*)alloc((size_t)n * 64 * 4);   // n x 128 bf16 (agg out)
    uint*   hA8    = (uint*)alloc((size_t)n * 32 * 4);   // n x 128 fp8 (gemm out)
    uint*   hC8    = (uint*)alloc((size_t)n * 16 * 4);   // n x 64 fp8
    ushort* WT0    = (ushort*)alloc(128 * 128 * 2);
    ushort* WT1    = (ushort*)alloc(128 * 128 * 2);
    ushort* WT2    = (ushort*)alloc(64 * 128 * 2);

    hipMemsetAsync(csr, 0, zbytes, stream);

    int PB = (16384 + 8192 + 255) / 256;       // prep blocks
    k_hist_prep<<<NT1 + PB, 256, 0, stream>>>(dstv, E, NT1, rank, C, NB, cnt,
                                              W0, W1, W2, WT0, WT1, WT2);
    k_cscan<<<NB, 64, 0, stream>>>(C, NT1, T);
    k_bscan<<<1, 64, 0, stream>>>(T, NB, tbase, cbase);

    int P = (E + 255) / 256;                   // place blocks
    int G = (n + 63) / 64;                     // gemm blocks
    // fused: edge scatter + layer-0 GEMM + node alloc (all independent)
    k_place_gemm_alloc<<<P + G + NB, 256, 0, stream>>>(srcv, dstv, E, NT1, rank, C,
                                                       tbase, tmp, P, G,
                                                       x, (const __bf16*)WT0, hA8,
                                                       cnt, cbase, offs, ends, dinv, n);
    k_p2<<<NB, 256, 0, stream>>>(tmp, tbase, offs, dinv, csr);

    int a8blocks = (n + 7) / 8;                // agg128: 8 nodes/block (2 per wave)
    int a4blocks = (n + 15) / 16;              // agg40: 16 nodes/block (4 per wave)

    // layer 0
    k_agg128<<<a8blocks, 256, 0, stream>>>(hA8, offs, ends, csr, dinv, b0, xb, n);
    // layer 1
    k_mgemm<128, false, true><<<G, 256, 0, stream>>>(xb, (const __bf16*)WT1, hA8, n);
    k_agg128<<<a8blocks, 256, 0, stream>>>(hA8, offs, ends, csr, dinv, b1, xb, n);
    // layer 2 + log_softmax
    k_mgemm<64, false, true><<<G, 256, 0, stream>>>(xb, (const __bf16*)WT2, hC8, n);
    k_agg40<<<a4blocks, 256, 0, stream>>>(hC8, offs, ends, csr, dinv, b2, out, n);
}

// Round 14
// 236.302 us; speedup vs baseline: 1.1027x; 1.1027x over previous
//
#include <hip/hip_runtime.h>
#include <math.h>

typedef unsigned int uint;
typedef unsigned short ushort;

typedef __bf16 bf16x8 __attribute__((ext_vector_type(8)));
typedef float f32x4 __attribute__((ext_vector_type(4)));
typedef float f32x2 __attribute__((ext_vector_type(2)));

#define MAXNB 512  // n < 65536 -> NB = ceil(n/128) <= 512

// ---------------- bf16 helpers (RNE pack, shift unpack) ----------------

__device__ inline uint bf16rne(float f) {
    uint u = __float_as_uint(f);
    uint r = ((u >> 16) & 1u) + 0x7fffu;
    return (u + r) >> 16;
}
__device__ inline uint packbf2(float a, float b) {
    return bf16rne(a) | (bf16rne(b) << 16);
}
__device__ inline float unhi(uint v) { return __uint_as_float(v & 0xffff0000u); }

// ---------------- graph prep: deterministic bucketed CSR build (R12 structure) --------
// bucket = dst>>7. Tiles of 2048 edges. No device-scope atomics anywhere.

// fused: [0..NT1) per-tile LDS histogram | [NT1..) weight prep
__global__ __launch_bounds__(256) void k_hist_prep(const int* __restrict__ dst, int E,
                                                   int NT1, ushort* __restrict__ rank,
                                                   int* __restrict__ C, int NB,
                                                   const float* __restrict__ W0,
                                                   const float* __restrict__ W1,
                                                   const float* __restrict__ W2,
                                                   ushort* __restrict__ WT0,
                                                   ushort* __restrict__ WT1,
                                                   ushort* __restrict__ WT2) {
    __shared__ int hist[MAXNB];
    int tid = threadIdx.x, b = blockIdx.x;
    if (b < NT1) {
        for (int i = tid; i < MAXNB; i += 256) hist[i] = 0;
        __syncthreads();
        int e0 = b * 2048;
#pragma unroll
        for (int i = 0; i < 8; ++i) {
            int e = e0 + i * 256 + tid;
            if (e < E) {
                int be = dst[e] >> 7;
                rank[e] = (ushort)atomicAdd(&hist[be], 1);  // LDS atomic
            }
        }
        __syncthreads();
        for (int be = tid; be < NB; be += 256) C[(size_t)be * NT1 + b] = hist[be];
    } else {
        int idx = (b - NT1) * 256 + tid;
        if (idx < 16384) {
            int c = idx >> 7, k = idx & 127;
            WT0[idx] = (ushort)bf16rne(W0[k * 128 + c]);
            WT1[idx] = (ushort)bf16rne(W1[k * 128 + c]);
        } else if (idx < 16384 + 8192) {
            int j = idx - 16384;
            int c = j >> 7, k = j & 127;
            WT2[j] = (c < 40) ? (ushort)bf16rne(W2[k * 40 + c]) : (ushort)0;
        }
    }
}

__global__ __launch_bounds__(64) void k_cscan(int* __restrict__ C, int NT1,
                                              int* __restrict__ T) {
    int be = blockIdx.x, lane = threadIdx.x;
    size_t base = (size_t)be * NT1;
    int carry = 0;
    for (int c0 = 0; c0 < NT1; c0 += 64) {
        int idx = c0 + lane;
        int v = (idx < NT1) ? C[base + idx] : 0;
        int s = v;
#pragma unroll
        for (int d = 1; d < 64; d <<= 1) {
            int o = __shfl_up(s, d);
            if (lane >= d) s += o;
        }
        if (idx < NT1) C[base + idx] = carry + s - v;
        carry += __shfl(s, 63);
    }
    if (lane == 0) T[be] = carry;
}

__global__ __launch_bounds__(64) void k_bscan(const int* __restrict__ T, int NB,
                                              int* __restrict__ tbase,
                                              int* __restrict__ cbase) {
    int lane = threadIdx.x;
    int c1 = 0, c2 = 0;
    for (int b0 = 0; b0 < NB; b0 += 64) {
        int idx = b0 + lane;
        int t = (idx < NB) ? T[idx] : 0;
        int u = t + 1024;
        int s1 = t, s2 = u;
#pragma unroll
        for (int d = 1; d < 64; d <<= 1) {
            int o1 = __shfl_up(s1, d), o2 = __shfl_up(s2, d);
            if (lane >= d) { s1 += o1; s2 += o2; }
        }
        if (idx < NB) { tbase[idx] = c1 + s1 - t; cbase[idx] = c2 + s2 - u; }
        c1 += __shfl(s1, 63);
        c2 += __shfl(s2, 63);
    }
    if (lane == 0) tbase[NB] = c1;
}

// block per bucket: node counts (LDS) -> 8-padded scan -> offs/ends/dinv
__global__ __launch_bounds__(256) void k_p2a(const uint* __restrict__ tmp,
                                             const int* __restrict__ tbase,
                                             const int* __restrict__ cbase,
                                             int* __restrict__ offs, int* __restrict__ ends,
                                             float* __restrict__ dinv, int n) {
    __shared__ int lcnt[128];
    __shared__ int sinc[128];
    int be = blockIdx.x, tid = threadIdx.x;
    if (tid < 128) lcnt[tid] = 0;
    __syncthreads();
    int j0 = tbase[be], j1 = tbase[be + 1];
    for (int j = j0 + tid; j < j1; j += 256)
        atomicAdd(&lcnt[tmp[j] >> 16], 1);
    __syncthreads();
    if (tid < 128) {
        int cp = (lcnt[tid] + 7) & ~7;
        int lane = tid & 63;
        int s = cp;
#pragma unroll
        for (int d = 1; d < 64; d <<= 1) {
            int o = __shfl_up(s, d);
            if (lane >= d) s += o;
        }
        sinc[tid] = s;  // inclusive within wave
    }
    __syncthreads();
    if (tid < 128) {
        int c = lcnt[tid];
        int cp = (c + 7) & ~7;
        int base = (tid >= 64) ? sinc[63] : 0;
        int og = cbase[be] + base + sinc[tid] - cp;
        int i = be * 128 + tid;
        if (i < n) {
            offs[i] = og;
            ends[i] = og + c;
            dinv[i] = rsqrtf((float)(c + 1));  // +1 self loop
        }
    }
}

// block per bucket: final scatter; all writes land in this bucket's csr window
// (single block = single XCD -> no false sharing). csr entry = {src:16 | bf16(w):16}.
__global__ __launch_bounds__(256) void k_p2b(const uint* __restrict__ tmp,
                                             const int* __restrict__ tbase,
                                             const int* __restrict__ offs,
                                             const float* __restrict__ dinv,
                                             uint* __restrict__ csr) {
    __shared__ int cur[128];
    int be = blockIdx.x, tid = threadIdx.x;
    if (tid < 128) cur[tid] = 0;
    __syncthreads();
    int j0 = tbase[be], j1 = tbase[be + 1];
    for (int j = j0 + tid; j < j1; j += 256) {
        uint v = tmp[j];
        int s = (int)(v & 0xffffu);
        int dl = (int)(v >> 16);
        int d = be * 128 + dl;
        int r = atomicAdd(&cur[dl], 1);  // LDS atomic
        uint wb = bf16rne(dinv[s] * dinv[d]) << 16;
        csr[offs[d] + r] = (uint)s | wb;
    }
}

// ---------------- MFMA GEMM body: H[n x F] = X[n x 128] @ W, WT = W^T[F x 128] ----
// wave = 16 rows x F cols; OUT8: pack D to fp8 e4m3 via quad shuffles + v_cvt_pk_fp8.
template <int F, bool F32IN, bool OUT8>
__device__ inline void mgemm_body(const void* __restrict__ Xv,
                                  const __bf16* __restrict__ WT,
                                  void* __restrict__ Hb, int n, int blk, int tid) {
    constexpr int NT = F / 16;  // 16-col tiles
    int lane = tid & 63;
    int wv = tid >> 6;
    int rbase = blk * 64 + wv * 16;
    if (rbase >= n) return;  // n % 16 == 0: strips fully valid or fully absent
    int m = lane & 15, quad = lane >> 4;

    bf16x8 a[4];
    if (F32IN) {
        const float* xrow = (const float*)Xv + (size_t)(rbase + m) * 128 + quad * 8;
#pragma unroll
        for (int ks = 0; ks < 4; ++ks) {
            float4 lo = *(const float4*)(xrow + ks * 32);
            float4 hi = *(const float4*)(xrow + ks * 32 + 4);
            union { ushort u[8]; bf16x8 v; } cv;
            cv.u[0] = (ushort)bf16rne(lo.x); cv.u[1] = (ushort)bf16rne(lo.y);
            cv.u[2] = (ushort)bf16rne(lo.z); cv.u[3] = (ushort)bf16rne(lo.w);
            cv.u[4] = (ushort)bf16rne(hi.x); cv.u[5] = (ushort)bf16rne(hi.y);
            cv.u[6] = (ushort)bf16rne(hi.z); cv.u[7] = (ushort)bf16rne(hi.w);
            a[ks] = cv.v;
        }
    } else {
        const __bf16* xrow = (const __bf16*)Xv + (size_t)(rbase + m) * 128 + quad * 8;
#pragma unroll
        for (int ks = 0; ks < 4; ++ks) a[ks] = *(const bf16x8*)(xrow + ks * 32);
    }

    f32x4 acc[NT];
#pragma unroll
    for (int t = 0; t < NT; ++t) acc[t] = (f32x4){0.f, 0.f, 0.f, 0.f};

#pragma unroll
    for (int t = 0; t < NT; ++t) {
        const __bf16* wrow = WT + (size_t)(t * 16 + m) * 128 + quad * 8;
#pragma unroll
        for (int ks = 0; ks < 4; ++ks) {
            bf16x8 b = *(const bf16x8*)(wrow + ks * 32);
            acc[t] = __builtin_amdgcn_mfma_f32_16x16x32_bf16(a[ks], b, acc[t], 0, 0, 0);
        }
    }

    if (OUT8) {
        uint* H8 = (uint*)Hb;  // row = F/4 uints (fp8 per feature)
#pragma unroll
        for (int t = 0; t < NT; ++t) {
#pragma unroll
            for (int r = 0; r < 4; ++r) {
                float v = acc[t][r];
                int s0 = lane & ~3;
                float v0 = __shfl(v, s0);
                float v1 = __shfl(v, s0 + 1);
                float v2 = __shfl(v, s0 + 2);
                float v3 = __shfl(v, s0 + 3);
                if ((m & 3) == 0) {
                    int pk = __builtin_amdgcn_cvt_pk_fp8_f32(v0, v1, 0, false);
                    pk = __builtin_amdgcn_cvt_pk_fp8_f32(v2, v3, pk, true);
                    int row = rbase + quad * 4 + r;
                    H8[(size_t)row * (F / 4) + t * 4 + (m >> 2)] = (uint)pk;
                }
            }
        }
    } else {
        ushort* Hs = (ushort*)Hb;
#pragma unroll
        for (int t = 0; t < NT; ++t) {
#pragma unroll
            for (int r = 0; r < 4; ++r) {
                int row = rbase + quad * 4 + r;
                Hs[(size_t)row * F + t * 16 + m] = (ushort)bf16rne(acc[t][r]);
            }
        }
    }
}

template <int F, bool F32IN, bool OUT8>
__global__ __launch_bounds__(256) void k_mgemm(const void* __restrict__ Xv,
                                               const __bf16* __restrict__ WT,
                                               void* __restrict__ Hb, int n) {
    mgemm_body<F, F32IN, OUT8>(Xv, WT, Hb, n, blockIdx.x, threadIdx.x);
}

// fused: [0..P) edge scatter into tmp (4B entries) | [P..P+G) layer-0 GEMM
__global__ __launch_bounds__(256) void k_place_gemm(const int* __restrict__ src,
                                                    const int* __restrict__ dst, int E,
                                                    int NT1, const ushort* __restrict__ rank,
                                                    const int* __restrict__ C,
                                                    const int* __restrict__ tbase,
                                                    uint* __restrict__ tmp, int P,
                                                    const float* __restrict__ x,
                                                    const __bf16* __restrict__ WT0,
                                                    uint* __restrict__ H8, int n) {
    int b = blockIdx.x;
    if (b < P) {
        int e = b * 256 + threadIdx.x;
        if (e >= E) return;
        int d = dst[e];
        int be = d >> 7, t = e >> 11;
        int pos = tbase[be] + C[(size_t)be * NT1 + t] + (int)rank[e];
        tmp[pos] = (uint)src[e] | ((uint)(d & 127) << 16);
    } else {
        mgemm_body<128, true, true>(x, WT0, H8, n, b - P, threadIdx.x);
    }
}

// ---------------- aggregation: y[i] = relu( sum_e w_e h[src_e] + dinv_i^2 h[i] + b ) --------
// fp8 h: row = 32 uints (128 fp8) = 2 lines/edge. wave = 2 nodes x 32 lanes;
// lane = 4 features. fp32 accumulate; bf16 packed out.
__global__ __launch_bounds__(256) void k_agg128(const uint* __restrict__ hb8,
                                                const int* __restrict__ offs,
                                                const int* __restrict__ ends,
                                                const uint* __restrict__ csr,
                                                const float* __restrict__ dinv,
                                                const float* __restrict__ bias,
                                                uint* __restrict__ out, int n) {
    int tid = threadIdx.x;
    int lane = tid & 63;
    int half = lane >> 5, l32 = lane & 31;
    int wid = blockIdx.x * 8 + ((tid >> 6) << 1) + half;
    if (wid >= n) return;
    float di = dinv[wid];
    float dd = di * di;
    uint t0 = hb8[(size_t)wid * 32 + l32];
    f32x2 s01 = __builtin_amdgcn_cvt_pk_f32_fp8((int)t0, false);
    f32x2 s23 = __builtin_amdgcn_cvt_pk_f32_fp8((int)t0, true);
    float4 acc = make_float4(s01[0] * dd, s01[1] * dd, s23[0] * dd, s23[1] * dd);
    int e0 = offs[wid];                       // multiple of 8
    int nchunk = (ends[wid] - e0 + 7) >> 3;
    const uint4* csrv = (const uint4*)(csr + e0);

    uint Pa[8], Pb[8];                        // packed {src | w_bf16}
    uint Ga[8], Gb[8];

    auto loadP = [&](int c, uint* p) {        // speculative final load stays in zero-pad
        uint4 v0 = csrv[2 * c];
        uint4 v1 = csrv[2 * c + 1];
        p[0] = v0.x; p[1] = v0.y; p[2] = v0.z; p[3] = v0.w;
        p[4] = v1.x; p[5] = v1.y; p[6] = v1.z; p[7] = v1.w;
    };
    auto gatherK = [&](const uint* p, uint* g) {
#pragma unroll
        for (int j = 0; j < 8; ++j)
            g[j] = hb8[(size_t)(p[j] & 0xffffu) * 32 + l32];
    };
    auto fmaK = [&](const uint* p, const uint* g) {
#pragma unroll
        for (int j = 0; j < 8; ++j) {
            float w = unhi(p[j]);
            f32x2 a01 = __builtin_amdgcn_cvt_pk_f32_fp8((int)g[j], false);
            f32x2 a23 = __builtin_amdgcn_cvt_pk_f32_fp8((int)g[j], true);
            acc.x = fmaf(w, a01[0], acc.x);
            acc.y = fmaf(w, a01[1], acc.y);
            acc.z = fmaf(w, a23[0], acc.z);
            acc.w = fmaf(w, a23[1], acc.w);
        }
    };

    if (nchunk > 0) {
        loadP(0, Pa);
        gatherK(Pa, Ga);
        loadP(1, Pb);
        int c = 0;
        while (true) {
            gatherK(Pb, Gb);   // chunk c+1 (entries pre-loaded)
            fmaK(Pa, Ga);      // chunk c (gathers issued an iter ago)
            if (++c >= nchunk) break;
            loadP(c + 1, Pa);
            gatherK(Pa, Ga);
            fmaK(Pb, Gb);
            if (++c >= nchunk) break;
            loadP(c + 1, Pb);
        }
    }

    float4 b = ((const float4*)bias)[l32];
    uint2 o;
    o.x = packbf2(fmaxf(acc.x + b.x, 0.f), fmaxf(acc.y + b.y, 0.f));
    o.y = packbf2(fmaxf(acc.z + b.z, 0.f), fmaxf(acc.w + b.w, 0.f));
    ((uint2*)out)[(size_t)wid * 32 + l32] = o;
}

// final layer: fp8 h (64 feats = 16 uints = 1 line/edge). wave = 4 nodes x 16 lanes,
// lane = 4 features; fused bias+relu+log_softmax over 16-lane groups (40 = 10 lanes x 4).
__global__ __launch_bounds__(256) void k_agg40(const uint* __restrict__ hb8,
                                               const int* __restrict__ offs,
                                               const int* __restrict__ ends,
                                               const uint* __restrict__ csr,
                                               const float* __restrict__ dinv,
                                               const float* __restrict__ bias,
                                               float* __restrict__ out, int n) {
    int tid = threadIdx.x;
    int lane = tid & 63;
    int quad = lane >> 4, l16 = lane & 15;
    int wid = blockIdx.x * 16 + ((tid >> 6) << 2) + quad;
    if (wid >= n) return;
    float di = dinv[wid];
    float dd = di * di;
    uint t0 = hb8[(size_t)wid * 16 + l16];
    f32x2 s01 = __builtin_amdgcn_cvt_pk_f32_fp8((int)t0, false);
    f32x2 s23 = __builtin_amdgcn_cvt_pk_f32_fp8((int)t0, true);
    float4 acc = make_float4(s01[0] * dd, s01[1] * dd, s23[0] * dd, s23[1] * dd);
    int e0 = offs[wid];                       // multiple of 8
    int nchunk = (ends[wid] - e0 + 7) >> 3;
    const uint4* csrv = (const uint4*)(csr + e0);

    uint Pa[8], Pb[8];
    uint Ga[8], Gb[8];

    auto loadP = [&](int c, uint* p) {        // quad-uniform broadcast loads
        uint4 v0 = csrv[2 * c];
        uint4 v1 = csrv[2 * c + 1];
        p[0] = v0.x; p[1] = v0.y; p[2] = v0.z; p[3] = v0.w;
        p[4] = v1.x; p[5] = v1.y; p[6] = v1.z; p[7] = v1.w;
    };
    auto gatherK = [&](const uint* p, uint* g) {
#pragma unroll
        for (int j = 0; j < 8; ++j)
            g[j] = hb8[(size_t)(p[j] & 0xffffu) * 16 + l16];
    };
    auto fmaK = [&](const uint* p, const uint* g) {
#pragma unroll
        for (int j = 0; j < 8; ++j) {
            float w = unhi(p[j]);
            f32x2 a01 = __builtin_amdgcn_cvt_pk_f32_fp8((int)g[j], false);
            f32x2 a23 = __builtin_amdgcn_cvt_pk_f32_fp8((int)g[j], true);
            acc.x = fmaf(w, a01[0], acc.x);
            acc.y = fmaf(w, a01[1], acc.y);
            acc.z = fmaf(w, a23[0], acc.z);
            acc.w = fmaf(w, a23[1], acc.w);
        }
    };

    if (nchunk > 0) {
        loadP(0, Pa);
        gatherK(Pa, Ga);
        loadP(1, Pb);
        int c = 0;
        while (true) {
            gatherK(Pb, Gb);
            fmaK(Pa, Ga);
            if (++c >= nchunk) break;
            loadP(c + 1, Pa);
            gatherK(Pa, Ga);
            fmaK(Pb, Gb);
            if (++c >= nchunk) break;
            loadP(c + 1, Pb);
        }
    }

    bool val = l16 < 10;                       // features l16*4..l16*4+3 valid iff l16<10
    float4 b4 = val ? ((const float4*)bias)[l16] : make_float4(0.f, 0.f, 0.f, 0.f);
    float v0 = val ? fmaxf(acc.x + b4.x, 0.f) : -INFINITY;
    float v1 = val ? fmaxf(acc.y + b4.y, 0.f) : -INFINITY;
    float v2 = val ? fmaxf(acc.z + b4.z, 0.f) : -INFINITY;
    float v3 = val ? fmaxf(acc.w + b4.w, 0.f) : -INFINITY;
    float m = fmaxf(fmaxf(v0, v1), fmaxf(v2, v3));
#pragma unroll
    for (int d = 8; d; d >>= 1) m = fmaxf(m, __shfl_xor(m, d));
    float ex = val ? (expf(v0 - m) + expf(v1 - m) + expf(v2 - m) + expf(v3 - m)) : 0.f;
#pragma unroll
    for (int d = 8; d; d >>= 1) ex += __shfl_xor(ex, d);
    float ls = logf(ex);
    if (val) {
        ((float4*)out)[(size_t)wid * 10 + l16] =
            make_float4(v0 - m - ls, v1 - m - ls, v2 - m - ls, v3 - m - ls);
    }
}

// ---------------- launch ----------------

extern "C" void kernel_launch(void* const* d_in, const int* in_sizes, int n_in,
                              void* d_out, int out_size, void* d_ws, size_t ws_size,
                              hipStream_t stream) {
    const float* x  = (const float*)d_in[0];
    const int*   ei = (const int*)d_in[1];
    const float* W0 = (const float*)d_in[2];
    const float* b0 = (const float*)d_in[3];
    const float* W1 = (const float*)d_in[4];
    const float* b1 = (const float*)d_in[5];
    const float* W2 = (const float*)d_in[6];
    const float* b2 = (const float*)d_in[7];
    float* out = (float*)d_out;

    int n = in_sizes[0] / 128;
    int E = in_sizes[1] / 2;
    const int* srcv = ei;
    const int* dstv = ei + E;
    int NB  = (n + 127) / 128;     // buckets (dst>>7), <= 512
    int NT1 = (E + 2047) / 2048;   // phase-1 tiles
    size_t csr_elems = (size_t)E + 1024 * (size_t)NB + 64;

    char* w = (char*)d_ws;
    auto alloc = [&](size_t bytes) {
        char* p = w;
        w += (bytes + 255) & ~(size_t)255;
        return p;
    };
    uint*   csr    = (uint*)alloc(csr_elems * 4);        // memset 0 (pads stay zero)
    int*    C      = (int*)alloc((size_t)NB * NT1 * 4);
    ushort* rank   = (ushort*)alloc((size_t)E * 2);
    uint*   tmp    = (uint*)alloc((size_t)E * 4);        // 4B entries {src:16|dl:16}
    int*    T      = (int*)alloc((size_t)NB * 4);
    int*    tbase  = (int*)alloc((size_t)(NB + 1) * 4);
    int*    cbase  = (int*)alloc((size_t)NB * 4);
    int*    offs   = (int*)alloc((size_t)n * 4);
    int*    ends   = (int*)alloc((size_t)n * 4);
    float*  dinv   = (float*)alloc((size_t)n * 4);
    uint*   xb     = (uint*)alloc((size_t)n * 64 * 4);   // n x 128 bf16 (agg out)
    uint*   hA8    = (uint*)alloc((size_t)n * 32 * 4);   // n x 128 fp8 (gemm out)
    uint*   hC8    = (uint*)alloc((size_t)n * 16 * 4);   // n x 64 fp8
    ushort* WT0    = (ushort*)alloc(128 * 128 * 2);
    ushort* WT1    = (ushort*)alloc(128 * 128 * 2);
    ushort* WT2    = (ushort*)alloc(64 * 128 * 2);

    hipMemsetAsync(csr, 0, csr_elems * 4, stream);

    int PB = (16384 + 8192 + 255) / 256;       // prep blocks
    k_hist_prep<<<NT1 + PB, 256, 0, stream>>>(dstv, E, NT1, rank, C, NB,
                                              W0, W1, W2, WT0, WT1, WT2);
    k_cscan<<<NB, 64, 0, stream>>>(C, NT1, T);
    k_bscan<<<1, 64, 0, stream>>>(T, NB, tbase, cbase);

    int P = (E + 255) / 256;                   // place blocks
    int G = (n + 63) / 64;                     // gemm blocks
    // fused: edge scatter + layer-0 GEMM (independent; overlap MFMA with scatter)
    k_place_gemm<<<P + G, 256, 0, stream>>>(srcv, dstv, E, NT1, rank, C, tbase, tmp, P,
                                            x, (const __bf16*)WT0, hA8, n);
    k_p2a<<<NB, 256, 0, stream>>>(tmp, tbase, cbase, offs, ends, dinv, n);
    k_p2b<<<NB, 256, 0, stream>>>(tmp, tbase, offs, dinv, csr);

    int a8blocks = (n + 7) / 8;                // agg128: 8 nodes/block (2 per wave)
    int a4blocks = (n + 15) / 16;              // agg40: 16 nodes/block (4 per wave)

    // layer 0
    k_agg128<<<a8blocks, 256, 0, stream>>>(hA8, offs, ends, csr, dinv, b0, xb, n);
    // layer 1
    k_mgemm<128, false, true><<<G, 256, 0, stream>>>(xb, (const __bf16*)WT1, hA8, n);
    k_agg128<<<a8blocks, 256, 0, stream>>>(hA8, offs, ends, csr, dinv, b1, xb, n);
    // layer 2 + log_softmax
    k_mgemm<64, false, true><<<G, 256, 0, stream>>>(xb, (const __bf16*)WT2, hC8, n);
    k_agg40<<<a4blocks, 256, 0, stream>>>(hC8, offs, ends, csr, dinv, b2, out, n);
}